// Round 1
// baseline (685.896 us; speedup 1.0000x reference)
//
#include <hip/hip_runtime.h>

#define BATCH 8
#define CH 128
#define NPIX 65536
#define PN 1024   // path_num
// psq = 64, channel = 128

// ---------------- K0: precompute M = Wq^T Wk, wqbk = Wq^T bk, wkbq = Wk^T bq, c0 = bq.bk
__global__ __launch_bounds__(256) void k0_precompute(
    const float* __restrict__ Wq, const float* __restrict__ bq,
    const float* __restrict__ Wk, const float* __restrict__ bk,
    float* __restrict__ M, float* __restrict__ wqbk,
    float* __restrict__ wkbq, float* __restrict__ c0) {
  int t = blockIdx.x * 256 + threadIdx.x;
  if (t < 16384) {
    int c = t >> 7, c2 = t & 127;
    float s = 0.f;
    for (int o = 0; o < 128; ++o) s += Wq[o * 128 + c] * Wk[o * 128 + c2];
    M[t] = s;
  } else if (t < 16512) {
    int c = t - 16384;
    float s = 0.f;
    for (int o = 0; o < 128; ++o) s += Wq[o * 128 + c] * bk[o];
    wqbk[c] = s;
  } else if (t < 16640) {
    int c = t - 16512;
    float s = 0.f;
    for (int o = 0; o < 128; ++o) s += bq[o] * Wk[o * 128 + c];
    wkbq[c] = s;
  } else if (t == 16640) {
    float s = 0.f;
    for (int o = 0; o < 128; ++o) s += bq[o] * bk[o];
    c0[0] = s;
  }
}

// ---------------- K1: channel mean+max, scatter into Hilbert/feat layout
// F[b][s*64+j][p] = stat_s(x[b,:,i]) where d = rehil[i], p = d>>6, j = d&63
__global__ __launch_bounds__(256) void k1_reduce_permute(
    const float* __restrict__ x, const int* __restrict__ rehil,
    float* __restrict__ F) {
  const int b = blockIdx.y;
  const int t = blockIdx.x * 256 + threadIdx.x;  // 0..16383
  const int i0 = t * 4;
  const float* xb = x + (size_t)b * CH * NPIX + i0;
  float4 s = make_float4(0.f, 0.f, 0.f, 0.f);
  float4 m = make_float4(-1e30f, -1e30f, -1e30f, -1e30f);
  for (int c = 0; c < CH; ++c) {
    const float4 v = *(const float4*)(xb + (size_t)c * NPIX);
    s.x += v.x; s.y += v.y; s.z += v.z; s.w += v.w;
    m.x = fmaxf(m.x, v.x); m.y = fmaxf(m.y, v.y);
    m.z = fmaxf(m.z, v.z); m.w = fmaxf(m.w, v.w);
  }
  const float inv = 1.f / (float)CH;
  float mean[4] = {s.x * inv, s.y * inv, s.z * inv, s.w * inv};
  float mx[4] = {m.x, m.y, m.z, m.w};
  const int4 d4 = *(const int4*)(rehil + i0);
  int ds[4] = {d4.x, d4.y, d4.z, d4.w};
  float* Fb = F + (size_t)b * CH * PN;
#pragma unroll
  for (int e = 0; e < 4; ++e) {
    int d = ds[e];
    int p = d >> 6, j = d & 63;
    Fb[j * PN + p] = mean[e];
    Fb[(64 + j) * PN + p] = mx[e];
  }
}

// ---------------- KU: u[b][p] = sum_c F[c,p]*wqbk[c];  v[b][q] = sum_c F[c,q]*wkbq[c]
__global__ __launch_bounds__(256) void ku_uv(
    const float* __restrict__ F, const float* __restrict__ wqbk,
    const float* __restrict__ wkbq, float* __restrict__ u, float* __restrict__ v) {
  const int b = blockIdx.y;
  const int p = blockIdx.x * 256 + threadIdx.x;  // 0..1023
  const float* Fb = F + (size_t)b * CH * PN;
  float su = 0.f, sv = 0.f;
  for (int c = 0; c < CH; ++c) {
    float f = Fb[c * PN + p];
    su = fmaf(f, wqbk[c], su);
    sv = fmaf(f, wkbq[c], sv);
  }
  u[b * PN + p] = su;
  v[b * PN + p] = sv;
}

// ---------------- K2: C = [M;Wv] * F (256x1024, K=128). rows<128 -> G[r][q];
// rows>=128 -> Vt[q][r-128] = C + bv[r-128]
__global__ __launch_bounds__(256) void k2_gv(
    const float* __restrict__ M, const float* __restrict__ Wv,
    const float* __restrict__ bv, const float* __restrict__ F,
    float* __restrict__ G, float* __restrict__ Vt) {
  __shared__ float As[16][64];
  __shared__ float Bs[16][64];
  const int b = blockIdx.z;
  const int r0 = blockIdx.y * 64;  // 0,64,128,192
  const int q0 = blockIdx.x * 64;
  const float* Fb = F + (size_t)b * CH * PN;
  const int t = threadIdx.x;
  const int tx = t & 15, ty = t >> 4;
  const int arow = t & 63, ak4 = (t >> 6) * 4;
  float acc[4][4] = {};
  for (int k0 = 0; k0 < 128; k0 += 16) {
    const int r = r0 + arow;
    const float* Arow = (r < 128) ? (M + r * 128) : (Wv + (r - 128) * 128);
    float4 a = *(const float4*)(Arow + k0 + ak4);
    As[ak4 + 0][arow] = a.x;
    As[ak4 + 1][arow] = a.y;
    As[ak4 + 2][arow] = a.z;
    As[ak4 + 3][arow] = a.w;
    *(float4*)&Bs[ty][tx * 4] =
        *(const float4*)(Fb + (size_t)(k0 + ty) * PN + q0 + tx * 4);
    __syncthreads();
#pragma unroll
    for (int kk = 0; kk < 16; ++kk) {
      float4 a4 = *(const float4*)&As[kk][ty * 4];
      float4 b4 = *(const float4*)&Bs[kk][tx * 4];
      float av[4] = {a4.x, a4.y, a4.z, a4.w};
      float bw[4] = {b4.x, b4.y, b4.z, b4.w};
#pragma unroll
      for (int i = 0; i < 4; ++i)
#pragma unroll
        for (int j = 0; j < 4; ++j) acc[i][j] = fmaf(av[i], bw[j], acc[i][j]);
    }
    __syncthreads();
  }
  float* Gb = G + (size_t)b * CH * PN;
  float* Vtb = Vt + (size_t)b * PN * CH;
#pragma unroll
  for (int i = 0; i < 4; ++i) {
    const int r = r0 + ty * 4 + i;
#pragma unroll
    for (int j = 0; j < 4; ++j) {
      const int q = q0 + tx * 4 + j;
      if (r < 128) Gb[r * PN + q] = acc[i][j];
      else Vtb[(size_t)q * CH + (r - 128)] = acc[i][j] + bv[r - 128];
    }
  }
}

// ---------------- K3: St[b][q][p] = sum_k G[k][q]*F[k][p] + u[p] + v[q] + c0
__global__ __launch_bounds__(256) void k3_scores(
    const float* __restrict__ G, const float* __restrict__ F,
    const float* __restrict__ u, const float* __restrict__ v,
    const float* __restrict__ c0, float* __restrict__ St) {
  __shared__ float As[16][64];  // G[k][q-tile]
  __shared__ float Bs[16][64];  // F[k][p-tile]
  const int b = blockIdx.z;
  const int q0 = blockIdx.y * 64;
  const int p0 = blockIdx.x * 64;
  const float* Gb = G + (size_t)b * CH * PN;
  const float* Fb = F + (size_t)b * CH * PN;
  const int t = threadIdx.x;
  const int tx = t & 15, ty = t >> 4;
  float acc[4][4] = {};
  for (int k0 = 0; k0 < 128; k0 += 16) {
    *(float4*)&As[ty][tx * 4] =
        *(const float4*)(Gb + (size_t)(k0 + ty) * PN + q0 + tx * 4);
    *(float4*)&Bs[ty][tx * 4] =
        *(const float4*)(Fb + (size_t)(k0 + ty) * PN + p0 + tx * 4);
    __syncthreads();
#pragma unroll
    for (int kk = 0; kk < 16; ++kk) {
      float4 a4 = *(const float4*)&As[kk][ty * 4];
      float4 b4 = *(const float4*)&Bs[kk][tx * 4];
      float av[4] = {a4.x, a4.y, a4.z, a4.w};
      float bw[4] = {b4.x, b4.y, b4.z, b4.w};
#pragma unroll
      for (int i = 0; i < 4; ++i)
#pragma unroll
        for (int j = 0; j < 4; ++j) acc[i][j] = fmaf(av[i], bw[j], acc[i][j]);
    }
    __syncthreads();
  }
  const float cc = c0[0];
  float* Sb = St + (size_t)b * PN * PN;
#pragma unroll
  for (int i = 0; i < 4; ++i) {
    const int q = q0 + ty * 4 + i;
    const float vq = v[b * PN + q] + cc;
#pragma unroll
    for (int j = 0; j < 4; ++j) {
      const int p = p0 + tx * 4 + j;
      Sb[(size_t)q * PN + p] = acc[i][j] + u[b * PN + p] + vq;
    }
  }
}

// ---------------- K4: per (b,q) row of St: m = max_p, invZ = 1/sum_p exp(s-m)
__global__ __launch_bounds__(256) void k4_softmax_stats(
    const float* __restrict__ St, float* __restrict__ mOut,
    float* __restrict__ izOut) {
  const int wid = threadIdx.x >> 6;
  const int lane = threadIdx.x & 63;
  const int row = blockIdx.x * 4 + wid;  // b*1024+q, 0..8191
  const float* Sr = St + (size_t)row * PN;
  float4 r[4];
  float m = -1e30f;
#pragma unroll
  for (int ch = 0; ch < 4; ++ch) {
    r[ch] = *(const float4*)(Sr + ch * 256 + lane * 4);
    m = fmaxf(m, fmaxf(fmaxf(r[ch].x, r[ch].y), fmaxf(r[ch].z, r[ch].w)));
  }
#pragma unroll
  for (int off = 32; off >= 1; off >>= 1) m = fmaxf(m, __shfl_xor(m, off));
  float z = 0.f;
#pragma unroll
  for (int ch = 0; ch < 4; ++ch) {
    z += __expf(r[ch].x - m) + __expf(r[ch].y - m) +
         __expf(r[ch].z - m) + __expf(r[ch].w - m);
  }
#pragma unroll
  for (int off = 32; off >= 1; off >>= 1) z += __shfl_xor(z, off);
  if (lane == 0) {
    mOut[row] = m;
    izOut[row] = 1.f / z;
  }
}

// ---------------- K5: x3c[c][p] = sum_q Vt[q][c] * exp(St[q][p]-m[q])*invZ[q]
__global__ __launch_bounds__(256) void k5_av(
    const float* __restrict__ Vt, const float* __restrict__ St,
    const float* __restrict__ mIn, const float* __restrict__ izIn,
    float* __restrict__ X3) {
  __shared__ float As[16][64];  // Vt[q][c-tile]
  __shared__ float Bs[16][64];  // E[q][p-tile]
  const int b = blockIdx.z;
  const int c0 = blockIdx.y * 64;  // 0 or 64
  const int p0 = blockIdx.x * 64;
  const float* Vtb = Vt + (size_t)b * PN * CH;
  const float* Sb = St + (size_t)b * PN * PN;
  const int t = threadIdx.x;
  const int tx = t & 15, ty = t >> 4;
  float acc[4][4] = {};
  for (int k0 = 0; k0 < PN; k0 += 16) {
    const int q = k0 + ty;
    *(float4*)&As[ty][tx * 4] =
        *(const float4*)(Vtb + (size_t)q * CH + c0 + tx * 4);
    const float mq = mIn[b * PN + q];
    const float iz = izIn[b * PN + q];
    const float4 sv = *(const float4*)(Sb + (size_t)q * PN + p0 + tx * 4);
    float4 ev;
    ev.x = __expf(sv.x - mq) * iz;
    ev.y = __expf(sv.y - mq) * iz;
    ev.z = __expf(sv.z - mq) * iz;
    ev.w = __expf(sv.w - mq) * iz;
    *(float4*)&Bs[ty][tx * 4] = ev;
    __syncthreads();
#pragma unroll
    for (int kk = 0; kk < 16; ++kk) {
      float4 a4 = *(const float4*)&As[kk][ty * 4];
      float4 b4 = *(const float4*)&Bs[kk][tx * 4];
      float av[4] = {a4.x, a4.y, a4.z, a4.w};
      float bw[4] = {b4.x, b4.y, b4.z, b4.w};
#pragma unroll
      for (int i = 0; i < 4; ++i)
#pragma unroll
        for (int j = 0; j < 4; ++j) acc[i][j] = fmaf(av[i], bw[j], acc[i][j]);
    }
    __syncthreads();
  }
  float* X3b = X3 + (size_t)b * CH * PN;
#pragma unroll
  for (int i = 0; i < 4; ++i)
#pragma unroll
    for (int j = 0; j < 4; ++j)
      X3b[(size_t)(c0 + ty * 4 + i) * PN + p0 + tx * 4 + j] = acc[i][j];
}

// ---------------- K7: gate = sigmoid(w0*x3c[j][p] + w1*x3c[64+j][p] + bpre); out = gate*x
__global__ __launch_bounds__(256) void k7_out(
    const float* __restrict__ x, const int* __restrict__ rehil,
    const float* __restrict__ X3, const float* __restrict__ Wpre,
    const float* __restrict__ bpre, float* __restrict__ out) {
  const int b = blockIdx.y;
  const int t = blockIdx.x * 256 + threadIdx.x;  // 0..16383
  const int i0 = t * 4;
  const float w0 = Wpre[0], w1 = Wpre[1], b0 = bpre[0];
  const int4 d4 = *(const int4*)(rehil + i0);
  const float* X3b = X3 + (size_t)b * CH * PN;
  int ds[4] = {d4.x, d4.y, d4.z, d4.w};
  float g[4];
#pragma unroll
  for (int e = 0; e < 4; ++e) {
    const int d = ds[e];
    const int p = d >> 6, j = d & 63;
    const float r0v = X3b[j * PN + p];
    const float r1v = X3b[(64 + j) * PN + p];
    const float logit = fmaf(w0, r0v, fmaf(w1, r1v, b0));
    g[e] = 1.f / (1.f + __expf(-logit));
  }
  const size_t base = (size_t)b * CH * NPIX + i0;
#pragma unroll 4
  for (int c = 0; c < CH; ++c) {
    const float4 v = *(const float4*)(x + base + (size_t)c * NPIX);
    float4 o;
    o.x = v.x * g[0];
    o.y = v.y * g[1];
    o.z = v.z * g[2];
    o.w = v.w * g[3];
    *(float4*)(out + base + (size_t)c * NPIX) = o;
  }
}

extern "C" void kernel_launch(void* const* d_in, const int* in_sizes, int n_in,
                              void* d_out, int out_size, void* d_ws,
                              size_t ws_size, hipStream_t stream) {
  const float* x = (const float*)d_in[0];
  const float* Wq = (const float*)d_in[1];
  const float* bq = (const float*)d_in[2];
  const float* Wk = (const float*)d_in[3];
  const float* bk = (const float*)d_in[4];
  const float* Wv = (const float*)d_in[5];
  const float* bv = (const float*)d_in[6];
  const float* Wpre = (const float*)d_in[7];
  const float* bpre = (const float*)d_in[8];
  const int* rehil = (const int*)d_in[10];
  float* out = (float*)d_out;
  float* ws = (float*)d_ws;

  // workspace layout (floats)
  const size_t SZ_FEAT = (size_t)BATCH * CH * PN;  // 1,048,576
  float* F = ws;
  float* G = F + SZ_FEAT;
  float* Vt = G + SZ_FEAT;
  float* X3 = Vt + SZ_FEAT;
  float* Mw = X3 + SZ_FEAT;           // 16384
  float* wqbk = Mw + 16384;           // 128
  float* wkbq = wqbk + 128;           // 128
  float* c0w = wkbq + 128;            // 1 (pad 64)
  float* uw = c0w + 64;               // 8192
  float* vw = uw + 8192;              // 8192
  float* mw = vw + 8192;              // 8192
  float* izw = mw + 8192;             // 8192
  float* Stw = izw + 8192;            // 8,388,608
  const size_t need = (size_t)(Stw - ws) + (size_t)BATCH * PN * PN;
  float* St = Stw;
  if (ws_size < need * sizeof(float)) {
    // fall back: score matrix lives in d_out (32 MB, same size); it is fully
    // consumed by k5 before k7 overwrites d_out with the real output.
    St = out;
  }

  k0_precompute<<<66, 256, 0, stream>>>(Wq, bq, Wk, bk, Mw, wqbk, wkbq, c0w);
  k1_reduce_permute<<<dim3(64, BATCH), 256, 0, stream>>>(x, rehil, F);
  ku_uv<<<dim3(4, BATCH), 256, 0, stream>>>(F, wqbk, wkbq, uw, vw);
  k2_gv<<<dim3(16, 4, BATCH), 256, 0, stream>>>(Mw, Wv, bv, F, G, Vt);
  k3_scores<<<dim3(16, 16, BATCH), 256, 0, stream>>>(G, F, uw, vw, c0w, St);
  k4_softmax_stats<<<2048, 256, 0, stream>>>(St, mw, izw);
  k5_av<<<dim3(16, 2, BATCH), 256, 0, stream>>>(Vt, St, mw, izw, X3);
  k7_out<<<dim3(64, BATCH), 256, 0, stream>>>(x, rehil, X3, Wpre, bpre, out);
}